// Round 1
// baseline (4014.547 us; speedup 1.0000x reference)
//
#include <hip/hip_runtime.h>

#define HS 50          // hidden size
#define TT 512         // timesteps
#define NB 4           // batch elements per wave
#define NWAVES 4       // waves per block
#define BLOCK (NWAVES*64)
#define KPAD 52        // k padded to multiple of 4 (k=50,51 are zeros)

__device__ __forceinline__ float fast_sigmoid(float x) {
    // 1/(1+exp(-x)) with fast exp2/rcp
    float e = __expf(-x);
    return __builtin_amdgcn_rcpf(1.0f + e);
}
__device__ __forceinline__ float fast_tanh(float x) {
    // 1 - 2/(exp(2x)+1); saturates gracefully at +-1
    float e = __expf(2.0f * x);
    return 1.0f - 2.0f * __builtin_amdgcn_rcpf(e + 1.0f);
}

__global__ __launch_bounds__(BLOCK, 1) void lstm_fused(
    const float* __restrict__ x,
    const float* __restrict__ wih1, const float* __restrict__ whh1,
    const float* __restrict__ bih1, const float* __restrict__ bhh1,
    const float* __restrict__ wih2, const float* __restrict__ whh2,
    const float* __restrict__ bih2, const float* __restrict__ bhh2,
    const float* __restrict__ fcw,  const float* __restrict__ fcb,
    float* __restrict__ out)
{
    // packed weights: wp[(k*HS + j)*4 + gate] = W[gate*HS + j][k], k in [0,KPAD) (k>=50 zero)
    __shared__ __align__(16) float wp1 [KPAD*HS*4];   // w_hh1   41.6 KB
    __shared__ __align__(16) float wp2i[KPAD*HS*4];   // w_ih2   41.6 KB
    __shared__ __align__(16) float wp2h[KPAD*HS*4];   // w_hh2   41.6 KB
    __shared__ __align__(16) float hb1[NWAVES][NB][KPAD];  // h1 broadcast, 3.3 KB
    __shared__ __align__(16) float hb2[NWAVES][NB][KPAD];  // h2 broadcast, 3.3 KB

    const int tid = threadIdx.x;

    // zero the padded weight arrays (covers k=50,51 pad lanes)
    for (int i = tid; i < KPAD*HS*4; i += BLOCK) { wp1[i]=0.f; wp2i[i]=0.f; wp2h[i]=0.f; }
    __syncthreads();
    // pack weights: coalesced global reads, scattered LDS writes (one-time)
    for (int i = tid; i < 4*HS*HS; i += BLOCK) {
        int r = i / HS, k = i % HS;      // r in [0,200)
        int grp = r / HS, j = r % HS;    // gate group, hidden index
        int d = (k*HS + j)*4 + grp;
        wp1[d]  = whh1[i];
        wp2i[d] = wih2[i];
        wp2h[d] = whh2[i];
    }
    __syncthreads();

    const int wid  = tid >> 6;
    const int lane = tid & 63;
    const int jb   = lane < HS ? lane : HS-1;   // clamp: lanes 50..63 duplicate lane 49
    const bool act = lane < HS;

    // per-lane parameters in registers
    float wih1v[4], bs1[4], bs2[4];
    #pragma unroll
    for (int g = 0; g < 4; ++g) {
        int r = g*HS + jb;
        wih1v[g] = wih1[r];              // w_ih1 is [200][1]
        bs1[g] = bih1[r] + bhh1[r];
        bs2[g] = bih2[r] + bhh2[r];
    }
    float fcwj = act ? fcw[jb] : 0.0f;

    const int gb0 = blockIdx.x * (NWAVES*NB) + wid*NB;  // global batch base of this wave

    // init h broadcast buffers to zero (incl. pad slots 50,51) — wave-private, no barrier
    if (lane < KPAD) {
        #pragma unroll
        for (int b = 0; b < NB; ++b) { hb1[wid][b][lane] = 0.f; hb2[wid][b][lane] = 0.f; }
    }

    float h1[NB], c1[NB], h2[NB], c2[NB];
    #pragma unroll
    for (int b = 0; b < NB; ++b) { h1[b]=0.f; c1[b]=0.f; h2[b]=0.f; c2[b]=0.f; }

    float xc[NB], xn[NB];
    #pragma unroll
    for (int b = 0; b < NB; ++b) xc[b] = x[(size_t)(gb0+b)*TT];

    for (int t = 0; t < TT; ++t) {
        // prefetch next x (broadcast load, hidden under compute)
        int tn = (t < TT-1) ? t+1 : TT-1;
        #pragma unroll
        for (int b = 0; b < NB; ++b) xn[b] = x[(size_t)(gb0+b)*TT + tn];

        // ---------------- layer 1: gates = x*w_ih1 + bsum + W_hh1 h1 ----------------
        float a1[NB][4];
        #pragma unroll
        for (int b = 0; b < NB; ++b) {
            #pragma unroll
            for (int g = 0; g < 4; ++g) a1[b][g] = fmaf(xc[b], wih1v[g], bs1[g]);
        }
        #pragma unroll
        for (int kk = 0; kk < KPAD; kk += 4) {
            float4 w0 = *(const float4*)&wp1[((kk+0)*HS + jb)*4];
            float4 w1 = *(const float4*)&wp1[((kk+1)*HS + jb)*4];
            float4 w2 = *(const float4*)&wp1[((kk+2)*HS + jb)*4];
            float4 w3 = *(const float4*)&wp1[((kk+3)*HS + jb)*4];
            #pragma unroll
            for (int b = 0; b < NB; ++b) {
                float4 hv = *(const float4*)&hb1[wid][b][kk];
                a1[b][0]=fmaf(w0.x,hv.x,a1[b][0]); a1[b][0]=fmaf(w1.x,hv.y,a1[b][0]);
                a1[b][0]=fmaf(w2.x,hv.z,a1[b][0]); a1[b][0]=fmaf(w3.x,hv.w,a1[b][0]);
                a1[b][1]=fmaf(w0.y,hv.x,a1[b][1]); a1[b][1]=fmaf(w1.y,hv.y,a1[b][1]);
                a1[b][1]=fmaf(w2.y,hv.z,a1[b][1]); a1[b][1]=fmaf(w3.y,hv.w,a1[b][1]);
                a1[b][2]=fmaf(w0.z,hv.x,a1[b][2]); a1[b][2]=fmaf(w1.z,hv.y,a1[b][2]);
                a1[b][2]=fmaf(w2.z,hv.z,a1[b][2]); a1[b][2]=fmaf(w3.z,hv.w,a1[b][2]);
                a1[b][3]=fmaf(w0.w,hv.x,a1[b][3]); a1[b][3]=fmaf(w1.w,hv.y,a1[b][3]);
                a1[b][3]=fmaf(w2.w,hv.z,a1[b][3]); a1[b][3]=fmaf(w3.w,hv.w,a1[b][3]);
            }
        }
        #pragma unroll
        for (int b = 0; b < NB; ++b) {
            float ig = fast_sigmoid(a1[b][0]);
            float fg = fast_sigmoid(a1[b][1]);
            float gg = fast_tanh   (a1[b][2]);
            float og = fast_sigmoid(a1[b][3]);
            c1[b] = fg*c1[b] + ig*gg;
            h1[b] = og * fast_tanh(c1[b]);
        }
        if (act) {
            #pragma unroll
            for (int b = 0; b < NB; ++b) hb1[wid][b][lane] = h1[b];  // new h1 for layer 2
        }

        // ---------------- layer 2: gates = W_ih2 h1_new + bsum + W_hh2 h2_old -------
        float a2[NB][4];
        #pragma unroll
        for (int b = 0; b < NB; ++b) {
            #pragma unroll
            for (int g = 0; g < 4; ++g) a2[b][g] = bs2[g];
        }
        #pragma unroll
        for (int kk = 0; kk < KPAD; kk += 4) {
            float4 wi0 = *(const float4*)&wp2i[((kk+0)*HS + jb)*4];
            float4 wi1 = *(const float4*)&wp2i[((kk+1)*HS + jb)*4];
            float4 wi2 = *(const float4*)&wp2i[((kk+2)*HS + jb)*4];
            float4 wi3 = *(const float4*)&wp2i[((kk+3)*HS + jb)*4];
            float4 wh0 = *(const float4*)&wp2h[((kk+0)*HS + jb)*4];
            float4 wh1_ = *(const float4*)&wp2h[((kk+1)*HS + jb)*4];
            float4 wh2_ = *(const float4*)&wp2h[((kk+2)*HS + jb)*4];
            float4 wh3_ = *(const float4*)&wp2h[((kk+3)*HS + jb)*4];
            #pragma unroll
            for (int b = 0; b < NB; ++b) {
                float4 hv1 = *(const float4*)&hb1[wid][b][kk];
                float4 hv2 = *(const float4*)&hb2[wid][b][kk];
                a2[b][0]=fmaf(wi0.x,hv1.x,a2[b][0]); a2[b][0]=fmaf(wi1.x,hv1.y,a2[b][0]);
                a2[b][0]=fmaf(wi2.x,hv1.z,a2[b][0]); a2[b][0]=fmaf(wi3.x,hv1.w,a2[b][0]);
                a2[b][0]=fmaf(wh0.x,hv2.x,a2[b][0]); a2[b][0]=fmaf(wh1_.x,hv2.y,a2[b][0]);
                a2[b][0]=fmaf(wh2_.x,hv2.z,a2[b][0]); a2[b][0]=fmaf(wh3_.x,hv2.w,a2[b][0]);
                a2[b][1]=fmaf(wi0.y,hv1.x,a2[b][1]); a2[b][1]=fmaf(wi1.y,hv1.y,a2[b][1]);
                a2[b][1]=fmaf(wi2.y,hv1.z,a2[b][1]); a2[b][1]=fmaf(wi3.y,hv1.w,a2[b][1]);
                a2[b][1]=fmaf(wh0.y,hv2.x,a2[b][1]); a2[b][1]=fmaf(wh1_.y,hv2.y,a2[b][1]);
                a2[b][1]=fmaf(wh2_.y,hv2.z,a2[b][1]); a2[b][1]=fmaf(wh3_.y,hv2.w,a2[b][1]);
                a2[b][2]=fmaf(wi0.z,hv1.x,a2[b][2]); a2[b][2]=fmaf(wi1.z,hv1.y,a2[b][2]);
                a2[b][2]=fmaf(wi2.z,hv1.z,a2[b][2]); a2[b][2]=fmaf(wi3.z,hv1.w,a2[b][2]);
                a2[b][2]=fmaf(wh0.z,hv2.x,a2[b][2]); a2[b][2]=fmaf(wh1_.z,hv2.y,a2[b][2]);
                a2[b][2]=fmaf(wh2_.z,hv2.z,a2[b][2]); a2[b][2]=fmaf(wh3_.z,hv2.w,a2[b][2]);
                a2[b][3]=fmaf(wi0.w,hv1.x,a2[b][3]); a2[b][3]=fmaf(wi1.w,hv1.y,a2[b][3]);
                a2[b][3]=fmaf(wi2.w,hv1.z,a2[b][3]); a2[b][3]=fmaf(wi3.w,hv1.w,a2[b][3]);
                a2[b][3]=fmaf(wh0.w,hv2.x,a2[b][3]); a2[b][3]=fmaf(wh1_.w,hv2.y,a2[b][3]);
                a2[b][3]=fmaf(wh2_.w,hv2.z,a2[b][3]); a2[b][3]=fmaf(wh3_.w,hv2.w,a2[b][3]);
            }
        }
        #pragma unroll
        for (int b = 0; b < NB; ++b) {
            float ig = fast_sigmoid(a2[b][0]);
            float fg = fast_sigmoid(a2[b][1]);
            float gg = fast_tanh   (a2[b][2]);
            float og = fast_sigmoid(a2[b][3]);
            c2[b] = fg*c2[b] + ig*gg;
            h2[b] = og * fast_tanh(c2[b]);
        }
        if (act) {
            #pragma unroll
            for (int b = 0; b < NB; ++b) hb2[wid][b][lane] = h2[b];  // for next timestep
        }
        #pragma unroll
        for (int b = 0; b < NB; ++b) xc[b] = xn[b];
    }

    // final FC: out[b] = fc_w . h2[b] + fc_b   (lanes >= 50 contribute 0)
    float fcb0 = fcb[0];
    #pragma unroll
    for (int b = 0; b < NB; ++b) {
        float v = fcwj * h2[b];
        #pragma unroll
        for (int off = 32; off > 0; off >>= 1) v += __shfl_xor(v, off);
        if (lane == 0) out[gb0 + b] = v + fcb0;
    }
}

extern "C" void kernel_launch(void* const* d_in, const int* in_sizes, int n_in,
                              void* d_out, int out_size, void* d_ws, size_t ws_size,
                              hipStream_t stream) {
    const float* x    = (const float*)d_in[0];
    const float* wih1 = (const float*)d_in[1];
    const float* whh1 = (const float*)d_in[2];
    const float* bih1 = (const float*)d_in[3];
    const float* bhh1 = (const float*)d_in[4];
    const float* wih2 = (const float*)d_in[5];
    const float* whh2 = (const float*)d_in[6];
    const float* bih2 = (const float*)d_in[7];
    const float* bhh2 = (const float*)d_in[8];
    const float* fcw  = (const float*)d_in[9];
    const float* fcb  = (const float*)d_in[10];
    float* out = (float*)d_out;

    int B = in_sizes[0] / TT;                 // 4096
    int grid = B / (NWAVES * NB);             // 256 blocks, 1 per CU
    hipLaunchKernelGGL(lstm_fused, dim3(grid), dim3(BLOCK), 0, stream,
                       x, wih1, whh1, bih1, bhh1, wih2, whh2, bih2, bhh2, fcw, fcb, out);
}

// Round 7
// 1882.335 us; speedup vs baseline: 2.1327x; 2.1327x over previous
//
#include <hip/hip_runtime.h>

#define HS 50          // hidden size
#define TT 512         // timesteps
#define NB 4           // batch elements per wave
#define NWAVES 4       // waves per block
#define BLOCK (NWAVES*64)
#define M 25           // k-pairs: k = 0..49 -> m = 0..24
#define JP 64          // j padded to 64 lanes (j>=50 weights are zero)
#define HBW (26*NB)    // hb dwords per wave; m==25 region is a write-dummy

typedef _Float16 half2_t __attribute__((ext_vector_type(2)));

__device__ __forceinline__ float dot2f(unsigned int w, unsigned int h, float c) {
    // v_dot2_f32_f16: c += w.lo*h.lo + w.hi*h.hi  (f32 accumulate)
    return __builtin_amdgcn_fdot2(__builtin_bit_cast(half2_t, w),
                                  __builtin_bit_cast(half2_t, h), c, false);
}

__device__ __forceinline__ float fast_sigmoid(float x) {
    float e = __expf(-x);
    return __builtin_amdgcn_rcpf(1.0f + e);
}
__device__ __forceinline__ float fast_tanh(float x) {
    float e = __expf(2.0f * x);
    return 1.0f - 2.0f * __builtin_amdgcn_rcpf(e + 1.0f);
}

__global__ __launch_bounds__(BLOCK, 1) void lstm_fused(
    const float* __restrict__ x,
    const float* __restrict__ wih1, const float* __restrict__ whh1,
    const float* __restrict__ bih1, const float* __restrict__ bhh1,
    const float* __restrict__ wih2, const float* __restrict__ whh2,
    const float* __restrict__ bih2, const float* __restrict__ bhh2,
    const float* __restrict__ fcw,  const float* __restrict__ fcb,
    float* __restrict__ out)
{
    // f16 k-pair packed weights: wp[m][g][j] dword = {W[g*HS+j][2m], W[g*HS+j][2m+1]}
    // lane-stride 4B -> conflict-free b32 reads; gate planes 64 dwords apart -> ds_read2_b32
    __shared__ __align__(16) unsigned int wp1 [M*4*JP];   // w_hh1  25.6 KB
    __shared__ __align__(16) unsigned int wp2i[M*4*JP];   // w_ih2  25.6 KB
    __shared__ __align__(16) unsigned int wp2h[M*4*JP];   // w_hh2  25.6 KB
    __shared__ __align__(16) unsigned int hb1[NWAVES][HBW];  // h1 f16 pairs [m][b]
    __shared__ __align__(16) unsigned int hb2[NWAVES][HBW];  // h2 f16 pairs [m][b]

    const int tid = threadIdx.x;

    // one-time pack: f32 global -> f16-pair LDS (zero for j >= HS)
    for (int d = tid; d < M*4*JP; d += BLOCK) {
        int j = d & 63, gm = d >> 6, g = gm & 3, m = gm >> 2;
        unsigned int v1 = 0, v2i = 0, v2h = 0;
        if (j < HS) {
            int r = (g*HS + j) * HS + 2*m;
            half2_t p1  = { (_Float16)whh1[r], (_Float16)whh1[r+1] };
            half2_t p2i = { (_Float16)wih2[r], (_Float16)wih2[r+1] };
            half2_t p2h = { (_Float16)whh2[r], (_Float16)whh2[r+1] };
            v1  = __builtin_bit_cast(unsigned int, p1);
            v2i = __builtin_bit_cast(unsigned int, p2i);
            v2h = __builtin_bit_cast(unsigned int, p2h);
        }
        wp1[d] = v1; wp2i[d] = v2i; wp2h[d] = v2h;
    }
    for (int i = tid; i < NWAVES*HBW; i += BLOCK) {
        (&hb1[0][0])[i] = 0u; (&hb2[0][0])[i] = 0u;
    }
    __syncthreads();

    const int wid  = tid >> 6;
    const int lane = tid & 63;
    const int jb   = lane < HS ? lane : HS-1;
    const bool act = lane < HS;

    float wih1v[4], bs1[4], bs2[4];
    #pragma unroll
    for (int g = 0; g < 4; ++g) {
        int r = g*HS + jb;
        wih1v[g] = wih1[r];
        bs1[g] = bih1[r] + bhh1[r];
        bs2[g] = bih2[r] + bhh2[r];
    }
    float fcwj = act ? fcw[jb] : 0.0f;

    const int gb0 = blockIdx.x * (NWAVES*NB) + wid*NB;

    // h-write slot: lane j writes f16 into pair m=j>>1, half j&1; lanes>=50 -> dummy m=25
    const int mw = (lane >> 1) < 25 ? (lane >> 1) : 25;
    _Float16* h1w = (_Float16*)&hb1[wid][0];
    _Float16* h2w = (_Float16*)&hb2[wid][0];

    float h1[NB], c1[NB], h2[NB], c2[NB];
    #pragma unroll
    for (int b = 0; b < NB; ++b) { h1[b]=0.f; c1[b]=0.f; h2[b]=0.f; c2[b]=0.f; }

    float xc[NB], xn[NB];
    #pragma unroll
    for (int b = 0; b < NB; ++b) xc[b] = x[(size_t)(gb0+b)*TT];

    for (int t = 0; t < TT; ++t) {
        int tn = (t < TT-1) ? t+1 : TT-1;
        #pragma unroll
        for (int b = 0; b < NB; ++b) xn[b] = x[(size_t)(gb0+b)*TT + tn];

        // ---------------- layer 1: a = x*w_ih1 + bsum + W_hh1 h1 ----------------
        float a1[NB][4];
        #pragma unroll
        for (int b = 0; b < NB; ++b) {
            #pragma unroll
            for (int g = 0; g < 4; ++g) a1[b][g] = fmaf(xc[b], wih1v[g], bs1[g]);
        }
        #pragma unroll
        for (int m = 0; m < M; ++m) {
            unsigned int w0 = wp1[(m*4+0)*JP + lane];
            unsigned int w1 = wp1[(m*4+1)*JP + lane];
            unsigned int w2 = wp1[(m*4+2)*JP + lane];
            unsigned int w3 = wp1[(m*4+3)*JP + lane];
            uint4 hv = *(const uint4*)&hb1[wid][m*NB];   // broadcast: pairs for b0..b3
            #pragma unroll
            for (int b = 0; b < NB; ++b) {
                unsigned int hp = (&hv.x)[b];
                a1[b][0] = dot2f(w0, hp, a1[b][0]);
                a1[b][1] = dot2f(w1, hp, a1[b][1]);
                a1[b][2] = dot2f(w2, hp, a1[b][2]);
                a1[b][3] = dot2f(w3, hp, a1[b][3]);
            }
        }
        #pragma unroll
        for (int b = 0; b < NB; ++b) {
            float ig = fast_sigmoid(a1[b][0]);
            float fg = fast_sigmoid(a1[b][1]);
            float gg = fast_tanh   (a1[b][2]);
            float og = fast_sigmoid(a1[b][3]);
            c1[b] = fg*c1[b] + ig*gg;
            h1[b] = og * fast_tanh(c1[b]);
            h1w[(mw*NB + b)*2 + (lane & 1)] = (_Float16)h1[b];
        }

        // ---------------- layer 2: a = W_ih2 h1_new + bsum + W_hh2 h2_old -------
        float a2[NB][4];
        #pragma unroll
        for (int b = 0; b < NB; ++b) {
            #pragma unroll
            for (int g = 0; g < 4; ++g) a2[b][g] = bs2[g];
        }
        #pragma unroll
        for (int m = 0; m < M; ++m) {
            unsigned int wi0 = wp2i[(m*4+0)*JP + lane];
            unsigned int wi1 = wp2i[(m*4+1)*JP + lane];
            unsigned int wi2 = wp2i[(m*4+2)*JP + lane];
            unsigned int wi3 = wp2i[(m*4+3)*JP + lane];
            unsigned int wh0 = wp2h[(m*4+0)*JP + lane];
            unsigned int wh1 = wp2h[(m*4+1)*JP + lane];
            unsigned int wh2 = wp2h[(m*4+2)*JP + lane];
            unsigned int wh3 = wp2h[(m*4+3)*JP + lane];
            uint4 hv1 = *(const uint4*)&hb1[wid][m*NB];
            uint4 hv2 = *(const uint4*)&hb2[wid][m*NB];
            #pragma unroll
            for (int b = 0; b < NB; ++b) {
                unsigned int hp1 = (&hv1.x)[b];
                unsigned int hp2 = (&hv2.x)[b];
                a2[b][0] = dot2f(wi0, hp1, a2[b][0]);
                a2[b][1] = dot2f(wi1, hp1, a2[b][1]);
                a2[b][2] = dot2f(wi2, hp1, a2[b][2]);
                a2[b][3] = dot2f(wi3, hp1, a2[b][3]);
                a2[b][0] = dot2f(wh0, hp2, a2[b][0]);
                a2[b][1] = dot2f(wh1, hp2, a2[b][1]);
                a2[b][2] = dot2f(wh2, hp2, a2[b][2]);
                a2[b][3] = dot2f(wh3, hp2, a2[b][3]);
            }
        }
        #pragma unroll
        for (int b = 0; b < NB; ++b) {
            float ig = fast_sigmoid(a2[b][0]);
            float fg = fast_sigmoid(a2[b][1]);
            float gg = fast_tanh   (a2[b][2]);
            float og = fast_sigmoid(a2[b][3]);
            c2[b] = fg*c2[b] + ig*gg;
            h2[b] = og * fast_tanh(c2[b]);
            h2w[(mw*NB + b)*2 + (lane & 1)] = (_Float16)h2[b];
        }
        #pragma unroll
        for (int b = 0; b < NB; ++b) xc[b] = xn[b];
    }

    // final FC: out[b] = fc_w . h2[b] + fc_b   (lanes >= 50 contribute 0)
    float fcb0 = fcb[0];
    #pragma unroll
    for (int b = 0; b < NB; ++b) {
        float v = fcwj * h2[b];
        #pragma unroll
        for (int off = 32; off > 0; off >>= 1) v += __shfl_xor(v, off);
        if (lane == 0) out[gb0 + b] = v + fcb0;
    }
}

extern "C" void kernel_launch(void* const* d_in, const int* in_sizes, int n_in,
                              void* d_out, int out_size, void* d_ws, size_t ws_size,
                              hipStream_t stream) {
    const float* x    = (const float*)d_in[0];
    const float* wih1 = (const float*)d_in[1];
    const float* whh1 = (const float*)d_in[2];
    const float* bih1 = (const float*)d_in[3];
    const float* bhh1 = (const float*)d_in[4];
    const float* wih2 = (const float*)d_in[5];
    const float* whh2 = (const float*)d_in[6];
    const float* bih2 = (const float*)d_in[7];
    const float* bhh2 = (const float*)d_in[8];
    const float* fcw  = (const float*)d_in[9];
    const float* fcb  = (const float*)d_in[10];
    float* out = (float*)d_out;

    int B = in_sizes[0] / TT;                 // 4096
    int grid = B / (NWAVES * NB);             // 256 blocks, 1 per CU
    hipLaunchKernelGGL(lstm_fused, dim3(grid), dim3(BLOCK), 0, stream,
                       x, wih1, whh1, bih1, bhh1, wih2, whh2, bih2, bhh2, fcw, fcb, out);
}